// Round 1
// baseline (177.291 us; speedup 1.0000x reference)
//
#include <hip/hip_runtime.h>
#include <math.h>

// Monotone cubic spline flow (neural spline flow, cubic variant).
// B*D = 2,097,152 elements, K = 8 bins.
// One thread per element; everything in registers, K-loops fully unrolled.

constexpr int K = 8;
constexpr float TAIL = 3.0f;
constexpr float MIN_BIN = 0.001f;
constexpr float SEARCH_EPS = 1e-6f;

__device__ __forceinline__ float signf(float v) {
    return (v > 0.0f ? 1.0f : (v < 0.0f ? -1.0f : 0.0f));
}

__global__ __launch_bounds__(256) void cbs_kernel(
    const float* __restrict__ x_,
    const float* __restrict__ w_,
    const float* __restrict__ h_,
    const float* __restrict__ dl_,
    const float* __restrict__ dr_,
    float* __restrict__ out,
    float* __restrict__ lad,
    int n)
{
    int i = blockIdx.x * blockDim.x + threadIdx.x;
    if (i >= n) return;

    // vector loads: 8 floats = 2 x float4 per row
    const float4* w4 = (const float4*)w_ + 2 * (size_t)i;
    const float4* h4 = (const float4*)h_ + 2 * (size_t)i;
    float4 wa = w4[0], wb = w4[1];
    float4 ha = h4[0], hb = h4[1];

    float wr[K] = {wa.x, wa.y, wa.z, wa.w, wb.x, wb.y, wb.z, wb.w};
    float hr[K] = {ha.x, ha.y, ha.z, ha.w, hb.x, hb.y, hb.z, hb.w};

    float xv  = x_[i];
    float dlv = dl_[i];
    float drv = dr_[i];

    // ---- softmax + min-bin affine: widths ----
    float mw = wr[0];
    #pragma unroll
    for (int k = 1; k < K; k++) mw = fmaxf(mw, wr[k]);
    float sw = 0.0f;
    #pragma unroll
    for (int k = 0; k < K; k++) { wr[k] = __expf(wr[k] - mw); sw += wr[k]; }
    float inv_sw = 1.0f / sw;
    #pragma unroll
    for (int k = 0; k < K; k++) wr[k] = MIN_BIN + (1.0f - MIN_BIN * K) * (wr[k] * inv_sw);

    // ---- softmax + min-bin affine: heights ----
    float mh = hr[0];
    #pragma unroll
    for (int k = 1; k < K; k++) mh = fmaxf(mh, hr[k]);
    float sh = 0.0f;
    #pragma unroll
    for (int k = 0; k < K; k++) { hr[k] = __expf(hr[k] - mh); sh += hr[k]; }
    float inv_sh = 1.0f / sh;
    #pragma unroll
    for (int k = 0; k < K; k++) hr[k] = MIN_BIN + (1.0f - MIN_BIN * K) * (hr[k] * inv_sh);

    // ---- cumulative knots (cw[0]=0; last knot handled as 1+eps in search) ----
    float cw[K + 1]; cw[0] = 0.0f;
    #pragma unroll
    for (int k = 0; k < K; k++) cw[k + 1] = cw[k] + wr[k];
    float ch[K + 1]; ch[0] = 0.0f;
    #pragma unroll
    for (int k = 0; k < K; k++) ch[k + 1] = ch[k] + hr[k];

    // ---- slopes ----
    float s[K];
    #pragma unroll
    for (int k = 0; k < K; k++) s[k] = hr[k] / wr[k];

    // ---- endpoint + interior derivatives ----
    float dv[K + 1];
    dv[0] = (1.0f / (1.0f + __expf(-dlv))) * 3.0f * s[0];
    dv[K] = (1.0f / (1.0f + __expf(-drv))) * 3.0f * s[K - 1];
    #pragma unroll
    for (int k = 0; k < K - 1; k++) {
        float m1 = fminf(fabsf(s[k]), fabsf(s[k + 1]));
        float m2 = 0.5f * (wr[k + 1] * s[k] + wr[k] * s[k + 1]) / (wr[k] + wr[k + 1]);
        float mn = fminf(m1, m2);
        dv[k + 1] = mn * (signf(s[k]) + signf(s[k + 1]));
    }

    // ---- normalized position & bin search ----
    float t = (xv + TAIL) / (2.0f * TAIL);
    t = fminf(fmaxf(t, 0.0f), 1.0f);

    int bin = 0;  // knots[0]=0 always <= t, so start count at 0 after the -1
    #pragma unroll
    for (int j = 1; j < K; j++) bin += (t >= cw[j]) ? 1 : 0;
    bin += (t >= 1.0f + SEARCH_EPS) ? 1 : 0;  // last knot = 1 + eps
    if (bin > K - 1) bin = K - 1;

    // ---- gather per-bin quantities (small select chains) ----
    float wk = wr[0], sk = s[0], d0 = dv[0], d1 = dv[1], lw = cw[0], dd = ch[0];
    #pragma unroll
    for (int k = 1; k < K; k++) {
        bool sel = (bin == k);
        wk = sel ? wr[k]     : wk;
        sk = sel ? s[k]      : sk;
        d0 = sel ? dv[k]     : d0;
        d1 = sel ? dv[k + 1] : d1;
        lw = sel ? cw[k]     : lw;
        dd = sel ? ch[k]     : dd;
    }

    float ia = (d0 + d1 - 2.0f * sk) / (wk * wk);
    float ib = (3.0f * sk - 2.0f * d0 - d1) / wk;
    float ic = d0;

    float sx = t - lw;
    float out_s = ((ia * sx + ib) * sx + ic) * sx + dd;
    float der   = (3.0f * ia * sx + 2.0f * ib) * sx + ic;
    float lad_s = __logf(fabsf(der));   // + log(6) - log(6) == 0

    out_s = fminf(fmaxf(out_s, 0.0f), 1.0f) * (2.0f * TAIL) - TAIL;

    bool inside = (xv >= -TAIL) && (xv <= TAIL);
    out[i] = inside ? out_s : xv;
    lad[i] = inside ? lad_s : 0.0f;
}

extern "C" void kernel_launch(void* const* d_in, const int* in_sizes, int n_in,
                              void* d_out, int out_size, void* d_ws, size_t ws_size,
                              hipStream_t stream) {
    const float* x  = (const float*)d_in[0];
    const float* w  = (const float*)d_in[1];
    const float* h  = (const float*)d_in[2];
    const float* dl = (const float*)d_in[3];
    const float* dr = (const float*)d_in[4];
    int n = in_sizes[0];               // 8192*256 = 2,097,152
    float* out = (float*)d_out;        // outputs, then logabsdet, concatenated
    float* lad = out + n;

    const int threads = 256;
    const int blocks = (n + threads - 1) / threads;
    cbs_kernel<<<blocks, threads, 0, stream>>>(x, w, h, dl, dr, out, lad, n);
}

// Round 2
// 174.995 us; speedup vs baseline: 1.0131x; 1.0131x over previous
//
#include <hip/hip_runtime.h>
#include <math.h>

// Monotone cubic spline flow (neural spline flow, cubic variant).
// B*D = 2,097,152 elements, K = 8 bins.
// One thread per element; everything in registers, K-loops fully unrolled.
// R2: all divides -> v_rcp_f32 + mul (threshold is loose; IEEE div sequences
// were ~170 VALU instrs/thread of pure overhead).

constexpr int K = 8;
constexpr float TAIL = 3.0f;
constexpr float MIN_BIN = 0.001f;
constexpr float SEARCH_EPS = 1e-6f;

__device__ __forceinline__ float rcpf(float v) {
    return __builtin_amdgcn_rcpf(v);   // v_rcp_f32, ~1 ulp
}

__device__ __forceinline__ float signf(float v) {
    return (v > 0.0f ? 1.0f : (v < 0.0f ? -1.0f : 0.0f));
}

__global__ __launch_bounds__(256) void cbs_kernel(
    const float* __restrict__ x_,
    const float* __restrict__ w_,
    const float* __restrict__ h_,
    const float* __restrict__ dl_,
    const float* __restrict__ dr_,
    float* __restrict__ out,
    float* __restrict__ lad,
    int n)
{
    int i = blockIdx.x * blockDim.x + threadIdx.x;
    if (i >= n) return;

    // vector loads: 8 floats = 2 x float4 per row
    const float4* w4 = (const float4*)w_ + 2 * (size_t)i;
    const float4* h4 = (const float4*)h_ + 2 * (size_t)i;
    float4 wa = w4[0], wb = w4[1];
    float4 ha = h4[0], hb = h4[1];

    float wr[K] = {wa.x, wa.y, wa.z, wa.w, wb.x, wb.y, wb.z, wb.w};
    float hr[K] = {ha.x, ha.y, ha.z, ha.w, hb.x, hb.y, hb.z, hb.w};

    float xv  = x_[i];
    float dlv = dl_[i];
    float drv = dr_[i];

    // ---- softmax + min-bin affine: widths ----
    float mw = wr[0];
    #pragma unroll
    for (int k = 1; k < K; k++) mw = fmaxf(mw, wr[k]);
    float sw = 0.0f;
    #pragma unroll
    for (int k = 0; k < K; k++) { wr[k] = __expf(wr[k] - mw); sw += wr[k]; }
    float inv_sw = rcpf(sw);
    #pragma unroll
    for (int k = 0; k < K; k++) wr[k] = MIN_BIN + (1.0f - MIN_BIN * K) * (wr[k] * inv_sw);

    // ---- softmax + min-bin affine: heights ----
    float mh = hr[0];
    #pragma unroll
    for (int k = 1; k < K; k++) mh = fmaxf(mh, hr[k]);
    float sh = 0.0f;
    #pragma unroll
    for (int k = 0; k < K; k++) { hr[k] = __expf(hr[k] - mh); sh += hr[k]; }
    float inv_sh = rcpf(sh);
    #pragma unroll
    for (int k = 0; k < K; k++) hr[k] = MIN_BIN + (1.0f - MIN_BIN * K) * (hr[k] * inv_sh);

    // ---- cumulative knots (cw[0]=0; last knot handled as 1+eps in search) ----
    float cw[K + 1]; cw[0] = 0.0f;
    #pragma unroll
    for (int k = 0; k < K; k++) cw[k + 1] = cw[k] + wr[k];
    float ch[K + 1]; ch[0] = 0.0f;
    #pragma unroll
    for (int k = 0; k < K; k++) ch[k + 1] = ch[k] + hr[k];

    // ---- slopes (rcp of widths reused nowhere else; trans pipe is idle) ----
    float s[K];
    #pragma unroll
    for (int k = 0; k < K; k++) s[k] = hr[k] * rcpf(wr[k]);

    // ---- endpoint + interior derivatives ----
    float dv[K + 1];
    dv[0] = rcpf(1.0f + __expf(-dlv)) * 3.0f * s[0];
    dv[K] = rcpf(1.0f + __expf(-drv)) * 3.0f * s[K - 1];
    #pragma unroll
    for (int k = 0; k < K - 1; k++) {
        float m1 = fminf(fabsf(s[k]), fabsf(s[k + 1]));
        float m2 = 0.5f * (wr[k + 1] * s[k] + wr[k] * s[k + 1]) * rcpf(wr[k] + wr[k + 1]);
        float mn = fminf(m1, m2);
        dv[k + 1] = mn * (signf(s[k]) + signf(s[k + 1]));
    }

    // ---- normalized position & bin search ----
    float t = (xv + TAIL) * (1.0f / (2.0f * TAIL));
    t = fminf(fmaxf(t, 0.0f), 1.0f);

    int bin = 0;  // knots[0]=0 always <= t, so start count at 0 after the -1
    #pragma unroll
    for (int j = 1; j < K; j++) bin += (t >= cw[j]) ? 1 : 0;
    bin += (t >= 1.0f + SEARCH_EPS) ? 1 : 0;  // last knot = 1 + eps
    if (bin > K - 1) bin = K - 1;

    // ---- gather per-bin quantities (small select chains) ----
    float wk = wr[0], sk = s[0], d0 = dv[0], d1 = dv[1], lw = cw[0], dd = ch[0];
    #pragma unroll
    for (int k = 1; k < K; k++) {
        bool sel = (bin == k);
        wk = sel ? wr[k]     : wk;
        sk = sel ? s[k]      : sk;
        d0 = sel ? dv[k]     : d0;
        d1 = sel ? dv[k + 1] : d1;
        lw = sel ? cw[k]     : lw;
        dd = sel ? ch[k]     : dd;
    }

    float inv_wk = rcpf(wk);
    float ia = (d0 + d1 - 2.0f * sk) * inv_wk * inv_wk;
    float ib = (3.0f * sk - 2.0f * d0 - d1) * inv_wk;
    float ic = d0;

    float sx = t - lw;
    float out_s = ((ia * sx + ib) * sx + ic) * sx + dd;
    float der   = (3.0f * ia * sx + 2.0f * ib) * sx + ic;
    float lad_s = __logf(fabsf(der));   // + log(6) - log(6) == 0

    out_s = fminf(fmaxf(out_s, 0.0f), 1.0f) * (2.0f * TAIL) - TAIL;

    bool inside = (xv >= -TAIL) && (xv <= TAIL);
    out[i] = inside ? out_s : xv;
    lad[i] = inside ? lad_s : 0.0f;
}

extern "C" void kernel_launch(void* const* d_in, const int* in_sizes, int n_in,
                              void* d_out, int out_size, void* d_ws, size_t ws_size,
                              hipStream_t stream) {
    const float* x  = (const float*)d_in[0];
    const float* w  = (const float*)d_in[1];
    const float* h  = (const float*)d_in[2];
    const float* dl = (const float*)d_in[3];
    const float* dr = (const float*)d_in[4];
    int n = in_sizes[0];               // 8192*256 = 2,097,152
    float* out = (float*)d_out;        // outputs, then logabsdet, concatenated
    float* lad = out + n;

    const int threads = 256;
    const int blocks = (n + threads - 1) / threads;
    cbs_kernel<<<blocks, threads, 0, stream>>>(x, w, h, dl, dr, out, lad, n);
}